// Round 1
// baseline (202.551 us; speedup 1.0000x reference)
//
#include <hip/hip_runtime.h>
#include <math.h>

#define NT 512
#define QDIM 4096   // 2^12

__device__ __forceinline__ int pairIdx(int p, int q) {
    return ((p >> q) << (q + 1)) | (p & ((1 << q) - 1));
}

// ---- 1q gates at bit q (LSB convention) ----
static __device__ __forceinline__ void ap_rx(float2* st, int tid, int q, float c, float s) {
#pragma unroll
    for (int it = 0; it < 2048 / NT; ++it) {
        int p = tid + it * NT;
        int k0 = pairIdx(p, q), k1 = k0 | (1 << q);
        float2 a = st[k0], b = st[k1];
        st[k0] = make_float2(c * a.x + s * b.y, c * a.y - s * b.x);
        st[k1] = make_float2(c * b.x + s * a.y, c * b.y - s * a.x);
    }
    __syncthreads();
}

static __device__ __forceinline__ void ap_ry(float2* st, int tid, int q, float c, float s) {
#pragma unroll
    for (int it = 0; it < 2048 / NT; ++it) {
        int p = tid + it * NT;
        int k0 = pairIdx(p, q), k1 = k0 | (1 << q);
        float2 a = st[k0], b = st[k1];
        st[k0] = make_float2(c * a.x - s * b.x, c * a.y - s * b.y);
        st[k1] = make_float2(s * a.x + c * b.x, s * a.y + c * b.y);
    }
    __syncthreads();
}

static __device__ __forceinline__ void ap_rz(float2* st, int tid, int q, float c, float s) {
#pragma unroll
    for (int it = 0; it < 2048 / NT; ++it) {
        int p = tid + it * NT;
        int k0 = pairIdx(p, q), k1 = k0 | (1 << q);
        float2 a = st[k0], b = st[k1];
        st[k0] = make_float2(a.x * c + a.y * s, a.y * c - a.x * s);  // * (c - i s)
        st[k1] = make_float2(b.x * c - b.y * s, b.y * c + b.x * s);  // * (c + i s)
    }
    __syncthreads();
}

// ---- 2q gates at bits (hi, lo), hi > lo (MSB-converted already) ----
static __device__ __forceinline__ void ap_zz(float2* st, int tid, int hi, int lo, float c, float s) {
#pragma unroll
    for (int it = 0; it < QDIM / NT; ++it) {
        int k = tid + it * NT;
        int u = (k >> hi) & 1, v = (k >> lo) & 1;
        float d = (u == v) ? -s : s;  // diag entry c + i*d
        float2 a = st[k];
        st[k] = make_float2(a.x * c - a.y * d, a.y * c + a.x * d);
    }
    __syncthreads();
}

static __device__ __forceinline__ void ap_xx(float2* st, int tid, int hi, int lo, float c, float s) {
    int mask = (1 << hi) | (1 << lo);
#pragma unroll
    for (int it = 0; it < 2048 / NT; ++it) {
        int p = tid + it * NT;
        int k0 = pairIdx(p, hi);  // bit hi == 0
        int k1 = k0 ^ mask;
        float2 a = st[k0], b = st[k1];
        // new = c*self - i*s*partner
        st[k0] = make_float2(c * a.x + s * b.y, c * a.y - s * b.x);
        st[k1] = make_float2(c * b.x + s * a.y, c * b.y - s * a.x);
    }
    __syncthreads();
}

static __device__ __forceinline__ void ap_yy(float2* st, int tid, int hi, int lo, float c, float s) {
    int mask = (1 << hi) | (1 << lo);
#pragma unroll
    for (int it = 0; it < 2048 / NT; ++it) {
        int p = tid + it * NT;
        int k0 = pairIdx(p, hi);  // bit hi == 0
        int k1 = k0 ^ mask;
        int v = (k0 >> lo) & 1;
        float sg = v ? -s : s;    // +i*s when u==v (u^v == 0), else -i*s
        float2 a = st[k0], b = st[k1];
        // new = c*self + i*sg*partner
        st[k0] = make_float2(c * a.x - sg * b.y, c * a.y + sg * b.x);
        st[k1] = make_float2(c * b.x - sg * a.y, c * b.y + sg * a.x);
    }
    __syncthreads();
}

static __device__ __forceinline__ void ap_cnot(float2* st, int tid, int hi, int lo) {
    // control = bit hi, target = bit lo (hi > lo always in this circuit)
#pragma unroll
    for (int it = 0; it < 1024 / NT; ++it) {
        int p = tid + it * NT;
        int low = p & ((1 << lo) - 1);
        int mid = (p >> lo) & ((1 << (hi - 1 - lo)) - 1);
        int top = p >> (hi - 1);
        int k = low | (mid << (lo + 1)) | (top << (hi + 1)) | (1 << hi);  // ctrl=1, tgt=0
        int k2 = k | (1 << lo);
        float2 a = st[k], b = st[k2];
        st[k] = b;
        st[k2] = a;
    }
    __syncthreads();
}

__global__ __launch_bounds__(NT) void qsim_kernel(
    const float* __restrict__ data,       // [64,12]
    const float* __restrict__ enc_scale,  // [12,3]
    const float* __restrict__ enc_bias,   // [12,3]
    const float* __restrict__ eta,        // [1,3]
    const float* __restrict__ ew_zz,      // [1,12]
    const float* __restrict__ ew_xx,      // [1,12]
    const float* __restrict__ ew_yy,      // [1,12]
    const float* __restrict__ nb_z,       // [1,12]
    const float* __restrict__ nb_x,       // [1,12]
    const float* __restrict__ nb_y,       // [1,12]
    const float* __restrict__ trots,      // [1,3,12,3]
    float* __restrict__ out)              // [64,12]
{
    __shared__ float2 st[QDIM];    // 32 KB state
    __shared__ float2 gp[216];     // (cos(t/2), sin(t/2)) per gate
    __shared__ float red[8][12];

    const int tid = threadIdx.x;
    const int bat = blockIdx.x;

    // ---- gate parameter table ----
    if (tid < 216) {
        float ang;
        if (tid < 36) {                       // encoding: [q][t], t=0 rx,1 ry,2 rz
            int q = tid / 3;
            ang = enc_scale[tid] * data[bat * 12 + q] + enc_bias[tid];
        } else if (tid < 72) {                // ising: [blk][e]
            int s2 = tid - 36; int bb = s2 / 12; int e = s2 % 12;
            const float* ew = (bb == 0) ? ew_zz : (bb == 1) ? ew_xx : ew_yy;
            ang = eta[bb] * ew[e];
        } else if (tid < 108) {               // node bias: [blk][q]
            int s2 = tid - 72; int bb = s2 / 12; int q = s2 % 12;
            const float* nb = (bb == 0) ? nb_z : (bb == 1) ? nb_x : nb_y;
            ang = nb[q];
        } else {                              // trainable rots: [blk][q][t] flat
            ang = trots[tid - 108];
        }
        float sv, cv;
        sincosf(0.5f * ang, &sv, &cv);
        gp[tid] = make_float2(cv, sv);
    }
    for (int k = tid; k < QDIM; k += NT)
        st[k] = make_float2(k == 0 ? 1.f : 0.f, 0.f);
    __syncthreads();

    // ---- circuit ----
    for (int blk = 0; blk < 3; ++blk) {
        // data encoding (full / xy / yz)
        for (int q = 0; q < 12; ++q) {
            float2 g;
            if (blk != 2) { g = gp[q * 3 + 0]; ap_rx(st, tid, q, g.x, g.y); }
            g = gp[q * 3 + 1]; ap_ry(st, tid, q, g.x, g.y);
            if (blk != 1) { g = gp[q * 3 + 2]; ap_rz(st, tid, q, g.x, g.y); }
        }
        // Ising interactions on ring edges (apply_2q: MSB convention, sorted qubits)
        for (int e = 0; e < 12; ++e) {
            int hi = (e < 11) ? (11 - e) : 11;
            int lo = (e < 11) ? (10 - e) : 0;
            float2 g = gp[36 + blk * 12 + e];
            if (blk == 0)      ap_zz(st, tid, hi, lo, g.x, g.y);
            else if (blk == 1) ap_xx(st, tid, hi, lo, g.x, g.y);
            else               ap_yy(st, tid, hi, lo, g.x, g.y);
        }
        // node biases (rz / rx / ry)
        for (int q = 0; q < 12; ++q) {
            float2 g = gp[72 + blk * 12 + q];
            if (blk == 0)      ap_rz(st, tid, q, g.x, g.y);
            else if (blk == 1) ap_rx(st, tid, q, g.x, g.y);
            else               ap_ry(st, tid, q, g.x, g.y);
        }
        // trainable rotations rx, ry, rz
        for (int q = 0; q < 12; ++q) {
            float2 g = gp[108 + blk * 36 + q * 3 + 0];
            ap_rx(st, tid, q, g.x, g.y);
            g = gp[108 + blk * 36 + q * 3 + 1];
            ap_ry(st, tid, q, g.x, g.y);
            g = gp[108 + blk * 36 + q * 3 + 2];
            ap_rz(st, tid, q, g.x, g.y);
        }
        // CNOT entangling ring
        for (int q = 0; q < 12; ++q) {
            int hi = (q < 11) ? (11 - q) : 11;
            int lo = (q < 11) ? (10 - q) : 0;
            ap_cnot(st, tid, hi, lo);
        }
    }

    // ---- Pauli-Z expectations: out[b][i] = sum_k |st[k]|^2 * (1 - 2*bit(11-i, k)) ----
    float acc[12];
#pragma unroll
    for (int i = 0; i < 12; ++i) acc[i] = 0.f;
#pragma unroll
    for (int it = 0; it < QDIM / NT; ++it) {
        int k = tid + it * NT;
        float2 a = st[k];
        float pr = a.x * a.x + a.y * a.y;
#pragma unroll
        for (int i = 0; i < 12; ++i)
            acc[i] += ((k >> (11 - i)) & 1) ? -pr : pr;
    }
#pragma unroll
    for (int off = 32; off > 0; off >>= 1)
#pragma unroll
        for (int i = 0; i < 12; ++i)
            acc[i] += __shfl_down(acc[i], off, 64);
    int lane = tid & 63, wv = tid >> 6;
    if (lane == 0)
#pragma unroll
        for (int i = 0; i < 12; ++i) red[wv][i] = acc[i];
    __syncthreads();
    if (tid < 12) {
        float s = 0.f;
#pragma unroll
        for (int w = 0; w < 8; ++w) s += red[w][tid];
        out[bat * 12 + tid] = s;
    }
}

extern "C" void kernel_launch(void* const* d_in, const int* in_sizes, int n_in,
                              void* d_out, int out_size, void* d_ws, size_t ws_size,
                              hipStream_t stream) {
    const float* data      = (const float*)d_in[0];
    const float* enc_scale = (const float*)d_in[1];
    const float* enc_bias  = (const float*)d_in[2];
    const float* eta       = (const float*)d_in[3];
    const float* ew_zz     = (const float*)d_in[4];
    const float* ew_xx     = (const float*)d_in[5];
    const float* ew_yy     = (const float*)d_in[6];
    const float* nb_z      = (const float*)d_in[7];
    const float* nb_x      = (const float*)d_in[8];
    const float* nb_y      = (const float*)d_in[9];
    const float* trots     = (const float*)d_in[10];
    float* out = (float*)d_out;

    int batch = out_size / 12;  // 64
    qsim_kernel<<<batch, NT, 0, stream>>>(data, enc_scale, enc_bias, eta,
                                          ew_zz, ew_xx, ew_yy,
                                          nb_z, nb_x, nb_y, trots, out);
}

// Round 2
// 117.010 us; speedup vs baseline: 1.7310x; 1.7310x over previous
//
#include <hip/hip_runtime.h>
#include <math.h>

#define NT 512
#define QDIM 4096   // 2^12

using F2 = float2;

__device__ __forceinline__ F2 cadd(F2 p, F2 q) { return make_float2(p.x + q.x, p.y + q.y); }
__device__ __forceinline__ F2 cmul(F2 p, F2 q) {
    return make_float2(p.x * q.x - p.y * q.y, p.x * q.y + p.y * q.x);
}

struct M2 { F2 a, b, c, d; };  // [[a,b],[c,d]]

__device__ __forceinline__ M2 mmul(M2 A, M2 B) {
    M2 R;
    R.a = cadd(cmul(A.a, B.a), cmul(A.b, B.c));
    R.b = cadd(cmul(A.a, B.b), cmul(A.b, B.d));
    R.c = cadd(cmul(A.c, B.a), cmul(A.d, B.c));
    R.d = cadd(cmul(A.c, B.b), cmul(A.d, B.d));
    return R;
}

__device__ __forceinline__ M2 mrx(float t) {
    float s, c; sincosf(0.5f * t, &s, &c);
    return { make_float2(c, 0), make_float2(0, -s), make_float2(0, -s), make_float2(c, 0) };
}
__device__ __forceinline__ M2 mry(float t) {
    float s, c; sincosf(0.5f * t, &s, &c);
    return { make_float2(c, 0), make_float2(-s, 0), make_float2(s, 0), make_float2(c, 0) };
}
__device__ __forceinline__ M2 mrz(float t) {
    float s, c; sincosf(0.5f * t, &s, &c);
    return { make_float2(c, -s), make_float2(0, 0), make_float2(0, 0), make_float2(c, s) };
}

// ---------- 1q gate sweeps ----------
// generic pair update: new0 = m00*x0 + m01*x1 ; new1 = m10*x0 + m11*x1

template<int Q>
__device__ __forceinline__ void g1_reg(F2* amp, const F2* g) {
    F2 m00 = g[0], m01 = g[1], m10 = g[2], m11 = g[3];
#pragma unroll
    for (int j = 0; j < 8; ++j)
        if (!(j & (1 << Q))) {
            F2 a = amp[j], b = amp[j | (1 << Q)];
            amp[j]            = cadd(cmul(m00, a), cmul(m01, b));
            amp[j | (1 << Q)] = cadd(cmul(m10, a), cmul(m11, b));
        }
}

template<int Q>
__device__ __forceinline__ void g1_shfl(F2* amp, const F2* g, int tid) {
    const int lm = 1 << (Q - 3);
    int u = (tid >> (Q - 3)) & 1;
    F2 ga = u ? g[2] : g[0], gb = u ? g[3] : g[1];
#pragma unroll
    for (int j = 0; j < 8; ++j) {
        F2 p;
        p.x = __shfl_xor(amp[j].x, lm, 64);
        p.y = __shfl_xor(amp[j].y, lm, 64);
        F2 x0 = u ? p : amp[j];
        F2 x1 = u ? amp[j] : p;
        amp[j] = cadd(cmul(ga, x0), cmul(gb, x1));
    }
}

template<int Q>
__device__ __forceinline__ void g1_lds(F2* amp, const F2* g, int tid, F2* b) {
#pragma unroll
    for (int j = 0; j < 8; ++j) b[j * 512 + tid] = amp[j];
    __syncthreads();
    int pt = tid ^ (1 << (Q - 3));
    int u  = (tid >> (Q - 3)) & 1;
    F2 ga = u ? g[2] : g[0], gb = u ? g[3] : g[1];
#pragma unroll
    for (int j = 0; j < 8; ++j) {
        F2 p  = b[j * 512 + pt];
        F2 x0 = u ? p : amp[j];
        F2 x1 = u ? amp[j] : p;
        amp[j] = cadd(cmul(ga, x0), cmul(gb, x1));
    }
}

// ---------- fused ZZ (all 12 edges, diagonal) ----------
__device__ __forceinline__ void zz_all(F2* amp, const float* zhalf, int tid) {
    float zr[12];
#pragma unroll
    for (int e = 0; e < 12; ++e) zr[e] = zhalf[e];
#pragma unroll
    for (int j = 0; j < 8; ++j) {
        int k = (tid << 3) | j;
        float phi = 0.f;
#pragma unroll
        for (int e = 0; e < 12; ++e) {
            int hi = (e < 11) ? 11 - e : 11, lo = (e < 11) ? 10 - e : 0;
            int par = ((k >> hi) ^ (k >> lo)) & 1;
            phi += par ? zr[e] : -zr[e];
        }
        float sp, cp;
        __sincosf(phi, &sp, &cp);
        amp[j] = cmul(amp[j], make_float2(cp, sp));
    }
}

// ---------- XX / YY edge sweeps: new(k) = c*amp[k] + i*d(k)*amp[k^mask] ----------
// XX: d = -s ;  YY: d = (parity(hi,lo bits of k)? -s : +s)

template<int HI, int LO, bool YY>
__device__ __forceinline__ void xy_reg(F2* amp, F2 cs, int tid) {
    const int jm = ((1 << HI) | (1 << LO)) & 7;
    float c = cs.x, s = cs.y;
    F2 old[8];
#pragma unroll
    for (int j = 0; j < 8; ++j) old[j] = amp[j];
#pragma unroll
    for (int j = 0; j < 8; ++j) {
        int k = (tid << 3) | j;
        int par = ((k >> HI) ^ (k >> LO)) & 1;
        float d = YY ? (par ? -s : s) : -s;
        F2 p = old[j ^ jm];
        amp[j] = make_float2(c * old[j].x - d * p.y, c * old[j].y + d * p.x);
    }
}

template<int HI, int LO, bool YY>
__device__ __forceinline__ void xy_shfl(F2* amp, F2 cs, int tid) {
    const int mask = (1 << HI) | (1 << LO);
    const int lm = mask >> 3, jm = mask & 7;
    float c = cs.x, s = cs.y;
    F2 pb[8];
#pragma unroll
    for (int j = 0; j < 8; ++j) {
        pb[j].x = __shfl_xor(amp[j].x, lm, 64);
        pb[j].y = __shfl_xor(amp[j].y, lm, 64);
    }
#pragma unroll
    for (int j = 0; j < 8; ++j) {
        int k = (tid << 3) | j;
        int par = ((k >> HI) ^ (k >> LO)) & 1;
        float d = YY ? (par ? -s : s) : -s;
        F2 p = pb[j ^ jm];
        amp[j] = make_float2(c * amp[j].x - d * p.y, c * amp[j].y + d * p.x);
    }
}

template<int HI, int LO, bool YY>
__device__ __forceinline__ void xy_lds(F2* amp, F2 cs, int tid, F2* b) {
    const int mask = (1 << HI) | (1 << LO);
    const int tx = mask >> 3, jm = mask & 7;
    float c = cs.x, s = cs.y;
#pragma unroll
    for (int j = 0; j < 8; ++j) b[j * 512 + tid] = amp[j];
    __syncthreads();
    int pt = tid ^ tx;
#pragma unroll
    for (int j = 0; j < 8; ++j) {
        int k = (tid << 3) | j;
        int par = ((k >> HI) ^ (k >> LO)) & 1;
        float d = YY ? (par ? -s : s) : -s;
        F2 p = b[(j ^ jm) * 512 + pt];
        amp[j] = make_float2(c * amp[j].x - d * p.y, c * amp[j].y + d * p.x);
    }
}

// ---------- fused CNOT ring: one permutation via LDS ----------
__device__ __forceinline__ void cnot_ring(F2* amp, int tid, F2* b) {
#pragma unroll
    for (int j = 0; j < 8; ++j) b[j * 512 + tid] = amp[j];
    __syncthreads();
#pragma unroll
    for (int j = 0; j < 8; ++j) {
        int k = (tid << 3) | j;
        // source index: S = f_{e=0}(f_{e=1}(...f_{e=11}(k)))
#pragma unroll
        for (int e = 11; e >= 0; --e) {
            int hi = (e < 11) ? 11 - e : 11, lo = (e < 11) ? 10 - e : 0;
            if ((k >> hi) & 1) k ^= (1 << lo);
        }
        amp[j] = b[(k & 7) * 512 + (k >> 3)];
    }
}

__global__ __launch_bounds__(NT) void qsim_kernel(
    const float* __restrict__ data,       // [64,12]
    const float* __restrict__ enc_scale,  // [12,3]
    const float* __restrict__ enc_bias,   // [12,3]
    const float* __restrict__ eta,        // [1,3]
    const float* __restrict__ ew_zz,      // [1,12]
    const float* __restrict__ ew_xx,      // [1,12]
    const float* __restrict__ ew_yy,      // [1,12]
    const float* __restrict__ nb_z,       // [1,12]
    const float* __restrict__ nb_x,       // [1,12]
    const float* __restrict__ nb_y,       // [1,12]
    const float* __restrict__ trots,      // [1,3,12,3]
    float* __restrict__ out)              // [64,12]
{
    __shared__ F2 buf[2][QDIM];   // 64 KB double buffer, layout slot(k) = (k&7)*512 + (k>>3)
    __shared__ F2 g1q[72][4];     // fused 1q matrices: [b*12+q] enc, [36+b*12+q] bias+trots
    __shared__ F2 gis[24];        // (cos,sin) for XX [0..11], YY [12..23]
    __shared__ float zhalf[12];   // theta/2 for ZZ edges
    __shared__ float red[8][12];

    const int tid = threadIdx.x;
    const int bat = blockIdx.x;

    // ---- precompute fused gate tables ----
    if (tid < 36) {                      // encoding: b = tid/12, q = tid%12
        int b = tid / 12, q = tid % 12;
        float x  = data[bat * 12 + q];
        float ax = enc_scale[q * 3 + 0] * x + enc_bias[q * 3 + 0];
        float ay = enc_scale[q * 3 + 1] * x + enc_bias[q * 3 + 1];
        float az = enc_scale[q * 3 + 2] * x + enc_bias[q * 3 + 2];
        M2 M;
        if (b == 0)      M = mmul(mrz(az), mmul(mry(ay), mrx(ax)));
        else if (b == 1) M = mmul(mry(ay), mrx(ax));
        else             M = mmul(mrz(az), mry(ay));
        g1q[tid][0] = M.a; g1q[tid][1] = M.b; g1q[tid][2] = M.c; g1q[tid][3] = M.d;
    } else if (tid < 72) {               // bias + trainables
        int i = tid - 36, b = i / 12, q = i % 12;
        float nb = (b == 0) ? nb_z[q] : (b == 1) ? nb_x[q] : nb_y[q];
        M2 M0 = (b == 0) ? mrz(nb) : (b == 1) ? mrx(nb) : mry(nb);
        float t0 = trots[(b * 12 + q) * 3 + 0];
        float t1 = trots[(b * 12 + q) * 3 + 1];
        float t2 = trots[(b * 12 + q) * 3 + 2];
        M2 M = mmul(mrz(t2), mmul(mry(t1), mmul(mrx(t0), M0)));
        g1q[tid][0] = M.a; g1q[tid][1] = M.b; g1q[tid][2] = M.c; g1q[tid][3] = M.d;
    } else if (tid < 96) {               // XX / YY (cos, sin) of theta/2
        int i = tid - 72, b = i / 12, e = i % 12;
        const float* ew = (b == 0) ? ew_xx : ew_yy;
        float th = eta[b + 1] * ew[e];
        float s, c; sincosf(0.5f * th, &s, &c);
        gis[i] = make_float2(c, s);
    } else if (tid < 108) {              // ZZ half-angles
        int e = tid - 96;
        zhalf[e] = 0.5f * eta[0] * ew_zz[e];
    }
    __syncthreads();

    // ---- state in registers: k = (tid<<3) | j ----
    F2 amp[8];
#pragma unroll
    for (int j = 0; j < 8; ++j) amp[j] = make_float2(0.f, 0.f);
    if (tid == 0) amp[0].x = 1.f;

    int sel = 0;
#define NEXTBUF (&buf[(sel ^= 1) ^ 1][0])

    for (int blk = 0; blk < 3; ++blk) {
        const F2(*Ge)[4] = &g1q[blk * 12];
        const F2(*Gb)[4] = &g1q[36 + blk * 12];

        // data encoding (fused per qubit)
        g1_reg<0>(amp, Ge[0]);  g1_reg<1>(amp, Ge[1]);  g1_reg<2>(amp, Ge[2]);
        g1_shfl<3>(amp, Ge[3], tid);  g1_shfl<4>(amp, Ge[4], tid);
        g1_shfl<5>(amp, Ge[5], tid);  g1_shfl<6>(amp, Ge[6], tid);
        g1_shfl<7>(amp, Ge[7], tid);  g1_shfl<8>(amp, Ge[8], tid);
        g1_lds<9>(amp, Ge[9], tid, NEXTBUF);
        g1_lds<10>(amp, Ge[10], tid, NEXTBUF);
        g1_lds<11>(amp, Ge[11], tid, NEXTBUF);

        // Ising interactions
        if (blk == 0) {
            zz_all(amp, zhalf, tid);
        } else if (blk == 1) {
            xy_lds<11,10,false>(amp, gis[0],  tid, NEXTBUF);
            xy_lds<10, 9,false>(amp, gis[1],  tid, NEXTBUF);
            xy_lds< 9, 8,false>(amp, gis[2],  tid, NEXTBUF);
            xy_shfl< 8, 7,false>(amp, gis[3],  tid);
            xy_shfl< 7, 6,false>(amp, gis[4],  tid);
            xy_shfl< 6, 5,false>(amp, gis[5],  tid);
            xy_shfl< 5, 4,false>(amp, gis[6],  tid);
            xy_shfl< 4, 3,false>(amp, gis[7],  tid);
            xy_shfl< 3, 2,false>(amp, gis[8],  tid);
            xy_reg < 2, 1,false>(amp, gis[9],  tid);
            xy_reg < 1, 0,false>(amp, gis[10], tid);
            xy_lds<11, 0,false>(amp, gis[11], tid, NEXTBUF);
        } else {
            xy_lds<11,10,true>(amp, gis[12], tid, NEXTBUF);
            xy_lds<10, 9,true>(amp, gis[13], tid, NEXTBUF);
            xy_lds< 9, 8,true>(amp, gis[14], tid, NEXTBUF);
            xy_shfl< 8, 7,true>(amp, gis[15], tid);
            xy_shfl< 7, 6,true>(amp, gis[16], tid);
            xy_shfl< 6, 5,true>(amp, gis[17], tid);
            xy_shfl< 5, 4,true>(amp, gis[18], tid);
            xy_shfl< 4, 3,true>(amp, gis[19], tid);
            xy_shfl< 3, 2,true>(amp, gis[20], tid);
            xy_reg < 2, 1,true>(amp, gis[21], tid);
            xy_reg < 1, 0,true>(amp, gis[22], tid);
            xy_lds<11, 0,true>(amp, gis[23], tid, NEXTBUF);
        }

        // node bias + trainable rotations (fused per qubit)
        g1_reg<0>(amp, Gb[0]);  g1_reg<1>(amp, Gb[1]);  g1_reg<2>(amp, Gb[2]);
        g1_shfl<3>(amp, Gb[3], tid);  g1_shfl<4>(amp, Gb[4], tid);
        g1_shfl<5>(amp, Gb[5], tid);  g1_shfl<6>(amp, Gb[6], tid);
        g1_shfl<7>(amp, Gb[7], tid);  g1_shfl<8>(amp, Gb[8], tid);
        g1_lds<9>(amp, Gb[9], tid, NEXTBUF);
        g1_lds<10>(amp, Gb[10], tid, NEXTBUF);
        g1_lds<11>(amp, Gb[11], tid, NEXTBUF);

        // CNOT entangling ring (fused permutation)
        cnot_ring(amp, tid, NEXTBUF);
    }

    // ---- Pauli-Z expectations ----
    float acc[12];
#pragma unroll
    for (int i = 0; i < 12; ++i) acc[i] = 0.f;
#pragma unroll
    for (int j = 0; j < 8; ++j) {
        int k = (tid << 3) | j;
        float pr = amp[j].x * amp[j].x + amp[j].y * amp[j].y;
#pragma unroll
        for (int i = 0; i < 12; ++i)
            acc[i] += ((k >> (11 - i)) & 1) ? -pr : pr;
    }
#pragma unroll
    for (int off = 32; off > 0; off >>= 1)
#pragma unroll
        for (int i = 0; i < 12; ++i)
            acc[i] += __shfl_down(acc[i], off, 64);
    int lane = tid & 63, wv = tid >> 6;
    if (lane == 0)
#pragma unroll
        for (int i = 0; i < 12; ++i) red[wv][i] = acc[i];
    __syncthreads();
    if (tid < 12) {
        float s = 0.f;
#pragma unroll
        for (int w = 0; w < 8; ++w) s += red[w][tid];
        out[bat * 12 + tid] = s;
    }
}

extern "C" void kernel_launch(void* const* d_in, const int* in_sizes, int n_in,
                              void* d_out, int out_size, void* d_ws, size_t ws_size,
                              hipStream_t stream) {
    const float* data      = (const float*)d_in[0];
    const float* enc_scale = (const float*)d_in[1];
    const float* enc_bias  = (const float*)d_in[2];
    const float* eta       = (const float*)d_in[3];
    const float* ew_zz     = (const float*)d_in[4];
    const float* ew_xx     = (const float*)d_in[5];
    const float* ew_yy     = (const float*)d_in[6];
    const float* nb_z      = (const float*)d_in[7];
    const float* nb_x      = (const float*)d_in[8];
    const float* nb_y      = (const float*)d_in[9];
    const float* trots     = (const float*)d_in[10];
    float* out = (float*)d_out;

    int batch = out_size / 12;  // 64
    qsim_kernel<<<batch, NT, 0, stream>>>(data, enc_scale, enc_bias, eta,
                                          ew_zz, ew_xx, ew_yy,
                                          nb_z, nb_x, nb_y, trots, out);
}

// Round 3
// 109.574 us; speedup vs baseline: 1.8485x; 1.0679x over previous
//
#include <hip/hip_runtime.h>
#include <math.h>

#define NT 512
#define QDIM 4096   // 2^12

using F2 = float2;

__device__ __forceinline__ F2 cadd(F2 p, F2 q) { return make_float2(p.x + q.x, p.y + q.y); }
__device__ __forceinline__ F2 cmul(F2 p, F2 q) {
    return make_float2(p.x * q.x - p.y * q.y, p.x * q.y + p.y * q.x);
}

struct M2 { F2 a, b, c, d; };  // [[a,b],[c,d]]

__device__ __forceinline__ M2 mmul(M2 A, M2 B) {
    M2 R;
    R.a = cadd(cmul(A.a, B.a), cmul(A.b, B.c));
    R.b = cadd(cmul(A.a, B.b), cmul(A.b, B.d));
    R.c = cadd(cmul(A.c, B.a), cmul(A.d, B.c));
    R.d = cadd(cmul(A.c, B.b), cmul(A.d, B.d));
    return R;
}

__device__ __forceinline__ M2 mrx(float t) {
    float s, c; sincosf(0.5f * t, &s, &c);
    return { make_float2(c, 0), make_float2(0, -s), make_float2(0, -s), make_float2(c, 0) };
}
__device__ __forceinline__ M2 mry(float t) {
    float s, c; sincosf(0.5f * t, &s, &c);
    return { make_float2(c, 0), make_float2(-s, 0), make_float2(s, 0), make_float2(c, 0) };
}
__device__ __forceinline__ M2 mrz(float t) {
    float s, c; sincosf(0.5f * t, &s, &c);
    return { make_float2(c, -s), make_float2(0, 0), make_float2(0, 0), make_float2(c, s) };
}

// ================= layouts =================
// L0: k = (tid<<3)|j        (j=q0-2, lanes=q3-8, waves=q9-11)
// L': k = (j<<9)|(l<<3)|w   (j=q9-11, lanes=q3-8, waves=q0-2)
// slot(k) = (k&7)*512 + (k>>3)  — uniform LDS addressing, conflict-free

// ---- 1q register gate on j-bit JB ----
template<int JB>
__device__ __forceinline__ void g1_reg(F2* amp, const F2* g) {
    const int m = 1 << JB;
    F2 m00 = g[0], m01 = g[1], m10 = g[2], m11 = g[3];
#pragma unroll
    for (int j = 0; j < 8; ++j)
        if (!(j & m)) {
            F2 a = amp[j], b = amp[j | m];
            amp[j]     = cadd(cmul(m00, a), cmul(m01, b));
            amp[j | m] = cadd(cmul(m10, a), cmul(m11, b));
        }
}

// ---- 1q shuffle gate on lane-mask LM (per-thread gs/gp, no per-amp select) ----
template<int LM>
__device__ __forceinline__ void g1_shfl(F2* amp, const F2* g, int lane) {
    bool u = (lane & LM) != 0;
    F2 gs = u ? g[3] : g[0];   // coeff on self
    F2 gp = u ? g[2] : g[1];   // coeff on partner
#pragma unroll
    for (int j = 0; j < 8; ++j) {
        F2 p;
        p.x = __shfl_xor(amp[j].x, LM, 64);
        p.y = __shfl_xor(amp[j].y, LM, 64);
        amp[j] = cadd(cmul(gs, amp[j]), cmul(gp, p));
    }
}

// ---- layout swaps (1 barrier each, double-buffered) ----
__device__ __forceinline__ void swap_to_Lp(F2* amp, int tid, int l, int w, F2* b) {
#pragma unroll
    for (int j = 0; j < 8; ++j) b[j * 512 + tid] = amp[j];          // slot(k), L0
    __syncthreads();
#pragma unroll
    for (int j = 0; j < 8; ++j) amp[j] = b[w * 512 + (j << 6) + l]; // slot(k), L'
}

__device__ __forceinline__ void swap_to_L0(F2* amp, int tid, int l, int w, F2* b) {
#pragma unroll
    for (int j = 0; j < 8; ++j) b[w * 512 + (j << 6) + l] = amp[j]; // slot(k), L'
    __syncthreads();
#pragma unroll
    for (int j = 0; j < 8; ++j) amp[j] = b[j * 512 + tid];          // slot(k), L0
}

// ================= Ising ops: new = c*self + i*d*partner =================
__device__ __forceinline__ F2 xyc(F2 a, F2 p, float c, float d) {
    return make_float2(fmaf(c, a.x, -d * p.y), fmaf(c, a.y, d * p.x));
}

// both qubit bits in j (bits B1 > B0)
template<int B1, int B0, bool YY>
__device__ __forceinline__ void xy_regj(F2* amp, F2 cs) {
    const int jm = (1 << B1) | (1 << B0);
    float c = cs.x, s = cs.y;
    F2 old[8];
#pragma unroll
    for (int j = 0; j < 8; ++j) old[j] = amp[j];
#pragma unroll
    for (int j = 0; j < 8; ++j) {
        int par = ((j >> B1) ^ (j >> B0)) & 1;
        float d = YY ? (par ? -s : s) : -s;
        amp[j] = xyc(old[j], old[j ^ jm], c, d);
    }
}

// both qubit bits in lanes (lane-bit positions LA > LB) — d is per-thread constant
template<int LA, int LB, bool YY>
__device__ __forceinline__ void xy_shl(F2* amp, F2 cs, int lane) {
    const int LM = (1 << LA) | (1 << LB);
    int par = ((lane >> LA) ^ (lane >> LB)) & 1;
    float c = cs.x;
    float d = YY ? (par ? -cs.y : cs.y) : -cs.y;
#pragma unroll
    for (int j = 0; j < 8; ++j) {
        F2 p;
        p.x = __shfl_xor(amp[j].x, LM, 64);
        p.y = __shfl_xor(amp[j].y, LM, 64);
        amp[j] = xyc(amp[j], p, c, d);
    }
}

// edge (9,8) in L': q9 = j bit0, q8 = lane bit5
template<bool YY>
__device__ __forceinline__ void xy_cross98(F2* amp, F2 cs, int lane) {
    float c = cs.x, s = cs.y;
    int lp = (lane >> 5) & 1;
    F2 old[8];
#pragma unroll
    for (int j = 0; j < 8; ++j) old[j] = amp[j];
#pragma unroll
    for (int j = 0; j < 8; ++j) {
        F2 p;
        p.x = __shfl_xor(old[j ^ 1].x, 32, 64);
        p.y = __shfl_xor(old[j ^ 1].y, 32, 64);
        int par = (j & 1) ^ lp;
        float d = YY ? (par ? -s : s) : -s;
        amp[j] = xyc(old[j], p, c, d);
    }
}

// edge (3,2) in L0: q3 = lane bit0, q2 = j bit2
template<bool YY>
__device__ __forceinline__ void xy_cross32(F2* amp, F2 cs, int lane) {
    float c = cs.x, s = cs.y;
    int lp = lane & 1;
    F2 old[8];
#pragma unroll
    for (int j = 0; j < 8; ++j) old[j] = amp[j];
#pragma unroll
    for (int j = 0; j < 8; ++j) {
        F2 p;
        p.x = __shfl_xor(old[j ^ 4].x, 1, 64);
        p.y = __shfl_xor(old[j ^ 4].y, 1, 64);
        int par = lp ^ ((j >> 2) & 1);
        float d = YY ? (par ? -s : s) : -s;
        amp[j] = xyc(old[j], p, c, d);
    }
}

// edge (11,0) in L0: q11 = tid bit8, q0 = j bit0 — via LDS pair exchange
template<bool YY>
__device__ __forceinline__ void xy_trip_11_0(F2* amp, F2 cs, int tid, F2* b) {
    float c = cs.x, s = cs.y;
    int wp = (tid >> 8) & 1;
#pragma unroll
    for (int j = 0; j < 8; ++j) b[j * 512 + tid] = amp[j];
    __syncthreads();
#pragma unroll
    for (int j = 0; j < 8; ++j) {
        F2 p = b[(j ^ 1) * 512 + (tid ^ 256)];
        int par = wp ^ (j & 1);
        float d = YY ? (par ? -s : s) : -s;
        amp[j] = xyc(amp[j], p, c, d);
    }
}

// fused ZZ (all 12 edges, diagonal) evaluated in L'
__device__ __forceinline__ void zz_all_Lp(F2* amp, const float* zhalf, int l, int w) {
    float zr[12];
#pragma unroll
    for (int e = 0; e < 12; ++e) zr[e] = zhalf[e];
#pragma unroll
    for (int j = 0; j < 8; ++j) {
        int k = (j << 9) | (l << 3) | w;
        float phi = 0.f;
#pragma unroll
        for (int e = 0; e < 12; ++e) {
            int hi = (e < 11) ? 11 - e : 11, lo = (e < 11) ? 10 - e : 0;
            phi += (((k >> hi) ^ (k >> lo)) & 1) ? zr[e] : -zr[e];
        }
        float sp, cp;
        __sincosf(phi, &sp, &cp);
        amp[j] = cmul(amp[j], make_float2(cp, sp));
    }
}

// composed CNOT-ring source index (sequential ring, fused to one permutation)
__device__ __forceinline__ int cnot_src(int k) {
#pragma unroll
    for (int e = 11; e >= 0; --e) {
        int hi = (e < 11) ? 11 - e : 11, lo = (e < 11) ? 10 - e : 0;
        if ((k >> hi) & 1) k ^= (1 << lo);
    }
    return k;
}

template<bool FROM_LP>
__device__ __forceinline__ void cnot_trip(F2* amp, int tid, int l, int w,
                                          const int* kslot, F2* b) {
#pragma unroll
    for (int j = 0; j < 8; ++j) {
        int slot = FROM_LP ? (w * 512 + (j << 6) + l) : (j * 512 + tid);
        b[slot] = amp[j];
    }
    __syncthreads();
#pragma unroll
    for (int j = 0; j < 8; ++j) amp[j] = b[kslot[j]];  // lands in L0
}

__global__ __launch_bounds__(NT) void qsim_kernel(
    const float* __restrict__ data,       // [64,12]
    const float* __restrict__ enc_scale,  // [12,3]
    const float* __restrict__ enc_bias,   // [12,3]
    const float* __restrict__ eta,        // [1,3]
    const float* __restrict__ ew_zz,      // [1,12]
    const float* __restrict__ ew_xx,      // [1,12]
    const float* __restrict__ ew_yy,      // [1,12]
    const float* __restrict__ nb_z,       // [1,12]
    const float* __restrict__ nb_x,       // [1,12]
    const float* __restrict__ nb_y,       // [1,12]
    const float* __restrict__ trots,      // [1,3,12,3]
    float* __restrict__ out)              // [64,12]
{
    __shared__ F2 buf[2][QDIM];   // 64 KB double buffer
    __shared__ F2 g1q[72][4];     // fused 1q matrices: enc [b*12+q], bias+trots [36+b*12+q]
    __shared__ F2 gis[24];        // (cos,sin) XX [0..11], YY [12..23]
    __shared__ float zhalf[12];
    __shared__ float red[8][12];

    const int tid = threadIdx.x;
    const int l = tid & 63, w = tid >> 6;
    const int bat = blockIdx.x;

    // ---- fused gate tables ----
    if (tid < 36) {                      // encoding: b = tid/12, q = tid%12
        int b = tid / 12, q = tid % 12;
        float x  = data[bat * 12 + q];
        float ax = enc_scale[q * 3 + 0] * x + enc_bias[q * 3 + 0];
        float ay = enc_scale[q * 3 + 1] * x + enc_bias[q * 3 + 1];
        float az = enc_scale[q * 3 + 2] * x + enc_bias[q * 3 + 2];
        M2 M;
        if (b == 0)      M = mmul(mrz(az), mmul(mry(ay), mrx(ax)));
        else if (b == 1) M = mmul(mry(ay), mrx(ax));
        else             M = mmul(mrz(az), mry(ay));
        g1q[tid][0] = M.a; g1q[tid][1] = M.b; g1q[tid][2] = M.c; g1q[tid][3] = M.d;
    } else if (tid < 72) {               // bias + trainables
        int i = tid - 36, b = i / 12, q = i % 12;
        float nb = (b == 0) ? nb_z[q] : (b == 1) ? nb_x[q] : nb_y[q];
        M2 M0 = (b == 0) ? mrz(nb) : (b == 1) ? mrx(nb) : mry(nb);
        float t0 = trots[(b * 12 + q) * 3 + 0];
        float t1 = trots[(b * 12 + q) * 3 + 1];
        float t2 = trots[(b * 12 + q) * 3 + 2];
        M2 M = mmul(mrz(t2), mmul(mry(t1), mmul(mrx(t0), M0)));
        g1q[tid][0] = M.a; g1q[tid][1] = M.b; g1q[tid][2] = M.c; g1q[tid][3] = M.d;
    } else if (tid < 96) {               // XX / YY (cos, sin) of theta/2
        int i = tid - 72, b = i / 12, e = i % 12;
        const float* ew = (b == 0) ? ew_xx : ew_yy;
        float th = eta[b + 1] * ew[e];
        float s, c; sincosf(0.5f * th, &s, &c);
        gis[i] = make_float2(c, s);
    } else if (tid < 108) {
        int e = tid - 96;
        zhalf[e] = 0.5f * eta[0] * ew_zz[e];
    }
    __syncthreads();

    // ---- state: L0, k = (tid<<3)|j ----
    F2 amp[8];
#pragma unroll
    for (int j = 0; j < 8; ++j) amp[j] = make_float2(0.f, 0.f);
    if (tid == 0) amp[0].x = 1.f;

    // precompute CNOT-ring gather slots (same permutation every block)
    int kslot[8];
#pragma unroll
    for (int j = 0; j < 8; ++j) {
        int ks = cnot_src((tid << 3) | j);
        kslot[j] = (ks & 7) * 512 + (ks >> 3);
    }

    int sel = 0;
#define NB (&buf[(sel ^= 1) ^ 1][0])

    for (int blk = 0; blk < 3; ++blk) {
        const F2(*Ge)[4] = &g1q[blk * 12];
        const F2(*Gb)[4] = &g1q[36 + blk * 12];

        // ---- data encoding: L0 regs, lane shfls, swap, L' regs -> end L' ----
        g1_reg<0>(amp, Ge[0]);  g1_reg<1>(amp, Ge[1]);  g1_reg<2>(amp, Ge[2]);
        g1_shfl<1>(amp, Ge[3], l);  g1_shfl<2>(amp, Ge[4], l);  g1_shfl<4>(amp, Ge[5], l);
        g1_shfl<8>(amp, Ge[6], l);  g1_shfl<16>(amp, Ge[7], l); g1_shfl<32>(amp, Ge[8], l);
        swap_to_Lp(amp, tid, l, w, NB);
        g1_reg<0>(amp, Ge[9]);  g1_reg<1>(amp, Ge[10]);  g1_reg<2>(amp, Ge[11]);

        if (blk == 0) {
            // ---- fused ZZ in L' ----
            zz_all_Lp(amp, zhalf, l, w);
            // ---- bias+trots: L' regs first, shfls, swap back, L0 regs ----
            g1_reg<0>(amp, Gb[9]);  g1_reg<1>(amp, Gb[10]);  g1_reg<2>(amp, Gb[11]);
            g1_shfl<1>(amp, Gb[3], l);  g1_shfl<2>(amp, Gb[4], l);  g1_shfl<4>(amp, Gb[5], l);
            g1_shfl<8>(amp, Gb[6], l);  g1_shfl<16>(amp, Gb[7], l); g1_shfl<32>(amp, Gb[8], l);
            swap_to_L0(amp, tid, l, w, NB);
            g1_reg<0>(amp, Gb[0]);  g1_reg<1>(amp, Gb[1]);  g1_reg<2>(amp, Gb[2]);
            cnot_trip<false>(amp, tid, l, w, kslot, NB);
        } else {
            // ---- XX/YY Ising (edges reordered; they mutually commute) ----
            const F2* G = (blk == 1) ? &gis[0] : &gis[12];
            if (blk == 1) {
                xy_regj<2,1,false>(amp, G[0]);            // (11,10)
                xy_regj<1,0,false>(amp, G[1]);            // (10,9)
                xy_cross98<false>(amp, G[2], l);          // (9,8)
                xy_shl<5,4,false>(amp, G[3], l);          // (8,7)
                xy_shl<4,3,false>(amp, G[4], l);          // (7,6)
                xy_shl<3,2,false>(amp, G[5], l);          // (6,5)
                xy_shl<2,1,false>(amp, G[6], l);          // (5,4)
                xy_shl<1,0,false>(amp, G[7], l);          // (4,3)
                swap_to_L0(amp, tid, l, w, NB);
                xy_cross32<false>(amp, G[8], l);          // (3,2)
                xy_regj<2,1,false>(amp, G[9]);            // (2,1)
                xy_regj<1,0,false>(amp, G[10]);           // (1,0)
                xy_trip_11_0<false>(amp, G[11], tid, NB); // (11,0)
            } else {
                xy_regj<2,1,true>(amp, G[0]);
                xy_regj<1,0,true>(amp, G[1]);
                xy_cross98<true>(amp, G[2], l);
                xy_shl<5,4,true>(amp, G[3], l);
                xy_shl<4,3,true>(amp, G[4], l);
                xy_shl<3,2,true>(amp, G[5], l);
                xy_shl<2,1,true>(amp, G[6], l);
                xy_shl<1,0,true>(amp, G[7], l);
                swap_to_L0(amp, tid, l, w, NB);
                xy_cross32<true>(amp, G[8], l);
                xy_regj<2,1,true>(amp, G[9]);
                xy_regj<1,0,true>(amp, G[10]);
                xy_trip_11_0<true>(amp, G[11], tid, NB);
            }
            // ---- bias+trots from L0: regs, shfls, swap, L' regs ----
            g1_reg<0>(amp, Gb[0]);  g1_reg<1>(amp, Gb[1]);  g1_reg<2>(amp, Gb[2]);
            g1_shfl<1>(amp, Gb[3], l);  g1_shfl<2>(amp, Gb[4], l);  g1_shfl<4>(amp, Gb[5], l);
            g1_shfl<8>(amp, Gb[6], l);  g1_shfl<16>(amp, Gb[7], l); g1_shfl<32>(amp, Gb[8], l);
            swap_to_Lp(amp, tid, l, w, NB);
            g1_reg<0>(amp, Gb[9]);  g1_reg<1>(amp, Gb[10]);  g1_reg<2>(amp, Gb[11]);
            cnot_trip<true>(amp, tid, l, w, kslot, NB);
        }
    }

    // ---- Pauli-Z expectations (state in L0) ----
    float acc[12];
#pragma unroll
    for (int i = 0; i < 12; ++i) acc[i] = 0.f;
#pragma unroll
    for (int j = 0; j < 8; ++j) {
        int k = (tid << 3) | j;
        float pr = amp[j].x * amp[j].x + amp[j].y * amp[j].y;
#pragma unroll
        for (int i = 0; i < 12; ++i)
            acc[i] += ((k >> (11 - i)) & 1) ? -pr : pr;
    }
#pragma unroll
    for (int off = 32; off > 0; off >>= 1)
#pragma unroll
        for (int i = 0; i < 12; ++i)
            acc[i] += __shfl_down(acc[i], off, 64);
    int wv = tid >> 6;
    if ((tid & 63) == 0)
#pragma unroll
        for (int i = 0; i < 12; ++i) red[wv][i] = acc[i];
    __syncthreads();
    if (tid < 12) {
        float s = 0.f;
#pragma unroll
        for (int ww = 0; ww < 8; ++ww) s += red[ww][tid];
        out[bat * 12 + tid] = s;
    }
}

extern "C" void kernel_launch(void* const* d_in, const int* in_sizes, int n_in,
                              void* d_out, int out_size, void* d_ws, size_t ws_size,
                              hipStream_t stream) {
    const float* data      = (const float*)d_in[0];
    const float* enc_scale = (const float*)d_in[1];
    const float* enc_bias  = (const float*)d_in[2];
    const float* eta       = (const float*)d_in[3];
    const float* ew_zz     = (const float*)d_in[4];
    const float* ew_xx     = (const float*)d_in[5];
    const float* ew_yy     = (const float*)d_in[6];
    const float* nb_z      = (const float*)d_in[7];
    const float* nb_x      = (const float*)d_in[8];
    const float* nb_y      = (const float*)d_in[9];
    const float* trots     = (const float*)d_in[10];
    float* out = (float*)d_out;

    int batch = out_size / 12;  // 64
    qsim_kernel<<<batch, NT, 0, stream>>>(data, enc_scale, enc_bias, eta,
                                          ew_zz, ew_xx, ew_yy,
                                          nb_z, nb_x, nb_y, trots, out);
}

// Round 4
// 106.190 us; speedup vs baseline: 1.9074x; 1.0319x over previous
//
#include <hip/hip_runtime.h>
#include <math.h>

#define NT 512
#define QDIM 4096   // 2^12

using F2 = float2;

__device__ __forceinline__ F2 cadd(F2 p, F2 q) { return make_float2(p.x + q.x, p.y + q.y); }
__device__ __forceinline__ F2 cmul(F2 p, F2 q) {
    return make_float2(p.x * q.x - p.y * q.y, p.x * q.y + p.y * q.x);
}

struct M2 { F2 a, b, c, d; };  // [[a,b],[c,d]]

__device__ __forceinline__ M2 mmul(M2 A, M2 B) {
    M2 R;
    R.a = cadd(cmul(A.a, B.a), cmul(A.b, B.c));
    R.b = cadd(cmul(A.a, B.b), cmul(A.b, B.d));
    R.c = cadd(cmul(A.c, B.a), cmul(A.d, B.c));
    R.d = cadd(cmul(A.c, B.b), cmul(A.d, B.d));
    return R;
}

__device__ __forceinline__ M2 mrx(float t) {
    float s, c; sincosf(0.5f * t, &s, &c);
    return { make_float2(c, 0), make_float2(0, -s), make_float2(0, -s), make_float2(c, 0) };
}
__device__ __forceinline__ M2 mry(float t) {
    float s, c; sincosf(0.5f * t, &s, &c);
    return { make_float2(c, 0), make_float2(-s, 0), make_float2(s, 0), make_float2(c, 0) };
}
__device__ __forceinline__ M2 mrz(float t) {
    float s, c; sincosf(0.5f * t, &s, &c);
    return { make_float2(c, -s), make_float2(0, 0), make_float2(0, 0), make_float2(c, s) };
}

#define RSQ2 0.70710678118654752f
// H = r*[[1,1],[1,-1]]
__device__ __forceinline__ M2 mH() {
    return { make_float2(RSQ2, 0), make_float2(RSQ2, 0), make_float2(RSQ2, 0), make_float2(-RSQ2, 0) };
}
// W = H*S = r*[[1,i],[1,-i]]   (S = diag(1,i)); W† Z W = -Y  =>  YY = W†⊗W† ZZ W⊗W
__device__ __forceinline__ M2 mW() {
    return { make_float2(RSQ2, 0), make_float2(0, RSQ2), make_float2(RSQ2, 0), make_float2(0, -RSQ2) };
}
// W† = S†*H = r*[[1,1],[-i,i]]
__device__ __forceinline__ M2 mWd() {
    return { make_float2(RSQ2, 0), make_float2(RSQ2, 0), make_float2(0, -RSQ2), make_float2(0, RSQ2) };
}

// ================= layouts =================
// L0: k = (tid<<3)|j        (j=q0-2, lanes=q3-8, waves=q9-11)
// L': k = (j<<9)|(l<<3)|w   (j=q9-11, lanes=q3-8, waves=q0-2)
// slot(k) = (k&7)*512 + (k>>3)  — uniform LDS addressing, conflict-free

template<int JB>
__device__ __forceinline__ void g1_reg(F2* amp, const F2* g) {
    const int m = 1 << JB;
    F2 m00 = g[0], m01 = g[1], m10 = g[2], m11 = g[3];
#pragma unroll
    for (int j = 0; j < 8; ++j)
        if (!(j & m)) {
            F2 a = amp[j], b = amp[j | m];
            amp[j]     = cadd(cmul(m00, a), cmul(m01, b));
            amp[j | m] = cadd(cmul(m10, a), cmul(m11, b));
        }
}

template<int LM>
__device__ __forceinline__ void g1_shfl(F2* amp, const F2* g, int lane) {
    bool u = (lane & LM) != 0;
    F2 gs = u ? g[3] : g[0];   // coeff on self
    F2 gp = u ? g[2] : g[1];   // coeff on partner
#pragma unroll
    for (int j = 0; j < 8; ++j) {
        F2 p;
        p.x = __shfl_xor(amp[j].x, LM, 64);
        p.y = __shfl_xor(amp[j].y, LM, 64);
        amp[j] = cadd(cmul(gs, amp[j]), cmul(gp, p));
    }
}

// ---- layout swaps (1 barrier each, double-buffered) ----
__device__ __forceinline__ void swap_to_Lp(F2* amp, int tid, int l, int w, F2* b) {
#pragma unroll
    for (int j = 0; j < 8; ++j) b[j * 512 + tid] = amp[j];          // slot(k), L0
    __syncthreads();
#pragma unroll
    for (int j = 0; j < 8; ++j) amp[j] = b[w * 512 + (j << 6) + l]; // slot(k), L'
}

__device__ __forceinline__ void swap_to_L0(F2* amp, int tid, int l, int w, F2* b) {
#pragma unroll
    for (int j = 0; j < 8; ++j) b[w * 512 + (j << 6) + l] = amp[j]; // slot(k), L'
    __syncthreads();
#pragma unroll
    for (int j = 0; j < 8; ++j) amp[j] = b[j * 512 + tid];          // slot(k), L0
}

// ---- fused diagonal Ising phase (all 12 edges) in L' ----
// entry(k) = exp(i*phi), phi = sum_e (bits of k at edge e differ ? +z_e : -z_e)
__device__ __forceinline__ void diag_all_Lp(F2* amp, const float* zhalf, int l, int w) {
    float zr[12];
#pragma unroll
    for (int e = 0; e < 12; ++e) zr[e] = zhalf[e];
#pragma unroll
    for (int j = 0; j < 8; ++j) {
        int k = (j << 9) | (l << 3) | w;
        float phi = 0.f;
#pragma unroll
        for (int e = 0; e < 12; ++e) {
            int hi = (e < 11) ? 11 - e : 11, lo = (e < 11) ? 10 - e : 0;
            phi += (((k >> hi) ^ (k >> lo)) & 1) ? zr[e] : -zr[e];
        }
        float sp, cp;
        __sincosf(phi, &sp, &cp);
        amp[j] = cmul(amp[j], make_float2(cp, sp));
    }
}

// composed CNOT-ring source index (sequential ring, fused to one permutation)
__device__ __forceinline__ int cnot_src(int k) {
#pragma unroll
    for (int e = 11; e >= 0; --e) {
        int hi = (e < 11) ? 11 - e : 11, lo = (e < 11) ? 10 - e : 0;
        if ((k >> hi) & 1) k ^= (1 << lo);
    }
    return k;
}

__device__ __forceinline__ void cnot_trip(F2* amp, int tid, const int* kslot, F2* b) {
#pragma unroll
    for (int j = 0; j < 8; ++j) b[j * 512 + tid] = amp[j];  // L0 slot(k)
    __syncthreads();
#pragma unroll
    for (int j = 0; j < 8; ++j) amp[j] = b[kslot[j]];       // lands in L0
}

__global__ __launch_bounds__(NT) void qsim_kernel(
    const float* __restrict__ data,       // [64,12]
    const float* __restrict__ enc_scale,  // [12,3]
    const float* __restrict__ enc_bias,   // [12,3]
    const float* __restrict__ eta,        // [1,3]
    const float* __restrict__ ew_zz,      // [1,12]
    const float* __restrict__ ew_xx,      // [1,12]
    const float* __restrict__ ew_yy,      // [1,12]
    const float* __restrict__ nb_z,       // [1,12]
    const float* __restrict__ nb_x,       // [1,12]
    const float* __restrict__ nb_y,       // [1,12]
    const float* __restrict__ trots,      // [1,3,12,3]
    float* __restrict__ out)              // [64,12]
{
    __shared__ F2 buf[2][QDIM];    // 64 KB double buffer
    __shared__ F2 g1q[72][4];      // fused 1q matrices: enc [b*12+q], bias+trots [36+b*12+q]
    __shared__ float zhalf[3][12]; // theta/2 per block, per edge
    __shared__ float red[8][12];

    const int tid = threadIdx.x;
    const int l = tid & 63, w = tid >> 6;
    const int bat = blockIdx.x;

    // ---- fused gate tables (basis changes folded in) ----
    if (tid < 36) {                      // encoding: b = tid/12, q = tid%12
        int b = tid / 12, q = tid % 12;
        float x  = data[bat * 12 + q];
        float ax = enc_scale[q * 3 + 0] * x + enc_bias[q * 3 + 0];
        float ay = enc_scale[q * 3 + 1] * x + enc_bias[q * 3 + 1];
        float az = enc_scale[q * 3 + 2] * x + enc_bias[q * 3 + 2];
        M2 M;
        if (b == 0)      M = mmul(mrz(az), mmul(mry(ay), mrx(ax)));   // ZZ block: no basis change
        else if (b == 1) M = mmul(mH(), mmul(mry(ay), mrx(ax)));      // XX: H after enc
        else             M = mmul(mW(), mmul(mrz(az), mry(ay)));      // YY: W after enc
        g1q[tid][0] = M.a; g1q[tid][1] = M.b; g1q[tid][2] = M.c; g1q[tid][3] = M.d;
    } else if (tid < 72) {               // bias + trainables (+ closing basis change first)
        int i = tid - 36, b = i / 12, q = i % 12;
        float nb = (b == 0) ? nb_z[q] : (b == 1) ? nb_x[q] : nb_y[q];
        M2 M0 = (b == 0) ? mrz(nb) : (b == 1) ? mrx(nb) : mry(nb);
        float t0 = trots[(b * 12 + q) * 3 + 0];
        float t1 = trots[(b * 12 + q) * 3 + 1];
        float t2 = trots[(b * 12 + q) * 3 + 2];
        M2 M = mmul(mrz(t2), mmul(mry(t1), mmul(mrx(t0), M0)));
        if (b == 1)      M = mmul(M, mH());    // H closes the XX sandwich (applied first)
        else if (b == 2) M = mmul(M, mWd());   // W† closes the YY sandwich
        g1q[tid][0] = M.a; g1q[tid][1] = M.b; g1q[tid][2] = M.c; g1q[tid][3] = M.d;
    } else if (tid < 108) {              // diagonal half-angles per block/edge
        int i = tid - 72, b = i / 12, e = i % 12;
        const float* ew = (b == 0) ? ew_zz : (b == 1) ? ew_xx : ew_yy;
        zhalf[b][e] = 0.5f * eta[b] * ew[e];
    }
    __syncthreads();

    // ---- state: L0, k = (tid<<3)|j ----
    F2 amp[8];
#pragma unroll
    for (int j = 0; j < 8; ++j) amp[j] = make_float2(0.f, 0.f);
    if (tid == 0) amp[0].x = 1.f;

    // precompute CNOT-ring gather slots (same permutation every block)
    int kslot[8];
#pragma unroll
    for (int j = 0; j < 8; ++j) {
        int ks = cnot_src((tid << 3) | j);
        kslot[j] = (ks & 7) * 512 + (ks >> 3);
    }

    int sel = 0;
#define NB (&buf[(sel ^= 1) ^ 1][0])

    for (int blk = 0; blk < 3; ++blk) {
        const F2(*Ge)[4] = &g1q[blk * 12];
        const F2(*Gb)[4] = &g1q[36 + blk * 12];

        // ---- encoding (+opening basis change): L0 regs, shfls, swap, L' regs ----
        g1_reg<0>(amp, Ge[0]);  g1_reg<1>(amp, Ge[1]);  g1_reg<2>(amp, Ge[2]);
        g1_shfl<1>(amp, Ge[3], l);  g1_shfl<2>(amp, Ge[4], l);  g1_shfl<4>(amp, Ge[5], l);
        g1_shfl<8>(amp, Ge[6], l);  g1_shfl<16>(amp, Ge[7], l); g1_shfl<32>(amp, Ge[8], l);
        swap_to_Lp(amp, tid, l, w, NB);
        g1_reg<0>(amp, Ge[9]);  g1_reg<1>(amp, Ge[10]);  g1_reg<2>(amp, Ge[11]);

        // ---- Ising block == fused diagonal in the rotated basis ----
        diag_all_Lp(amp, zhalf[blk], l, w);

        // ---- (closing basis change+) bias + trots: L' regs, shfls, swap, L0 regs ----
        g1_reg<0>(amp, Gb[9]);  g1_reg<1>(amp, Gb[10]);  g1_reg<2>(amp, Gb[11]);
        g1_shfl<1>(amp, Gb[3], l);  g1_shfl<2>(amp, Gb[4], l);  g1_shfl<4>(amp, Gb[5], l);
        g1_shfl<8>(amp, Gb[6], l);  g1_shfl<16>(amp, Gb[7], l); g1_shfl<32>(amp, Gb[8], l);
        swap_to_L0(amp, tid, l, w, NB);
        g1_reg<0>(amp, Gb[0]);  g1_reg<1>(amp, Gb[1]);  g1_reg<2>(amp, Gb[2]);

        // ---- CNOT entangling ring (fused permutation) ----
        cnot_trip(amp, tid, kslot, NB);
    }

    // ---- Pauli-Z expectations (state in L0) ----
    float acc[12];
#pragma unroll
    for (int i = 0; i < 12; ++i) acc[i] = 0.f;
#pragma unroll
    for (int j = 0; j < 8; ++j) {
        int k = (tid << 3) | j;
        float pr = amp[j].x * amp[j].x + amp[j].y * amp[j].y;
#pragma unroll
        for (int i = 0; i < 12; ++i)
            acc[i] += ((k >> (11 - i)) & 1) ? -pr : pr;
    }
#pragma unroll
    for (int off = 32; off > 0; off >>= 1)
#pragma unroll
        for (int i = 0; i < 12; ++i)
            acc[i] += __shfl_down(acc[i], off, 64);
    int wv = tid >> 6;
    if ((tid & 63) == 0)
#pragma unroll
        for (int i = 0; i < 12; ++i) red[wv][i] = acc[i];
    __syncthreads();
    if (tid < 12) {
        float s = 0.f;
#pragma unroll
        for (int ww = 0; ww < 8; ++ww) s += red[ww][tid];
        out[bat * 12 + tid] = s;
    }
}

extern "C" void kernel_launch(void* const* d_in, const int* in_sizes, int n_in,
                              void* d_out, int out_size, void* d_ws, size_t ws_size,
                              hipStream_t stream) {
    const float* data      = (const float*)d_in[0];
    const float* enc_scale = (const float*)d_in[1];
    const float* enc_bias  = (const float*)d_in[2];
    const float* eta       = (const float*)d_in[3];
    const float* ew_zz     = (const float*)d_in[4];
    const float* ew_xx     = (const float*)d_in[5];
    const float* ew_yy     = (const float*)d_in[6];
    const float* nb_z      = (const float*)d_in[7];
    const float* nb_x      = (const float*)d_in[8];
    const float* nb_y      = (const float*)d_in[9];
    const float* trots     = (const float*)d_in[10];
    float* out = (float*)d_out;

    int batch = out_size / 12;  // 64
    qsim_kernel<<<batch, NT, 0, stream>>>(data, enc_scale, enc_bias, eta,
                                          ew_zz, ew_xx, ew_yy,
                                          nb_z, nb_x, nb_y, trots, out);
}

// Round 5
// 103.262 us; speedup vs baseline: 1.9615x; 1.0284x over previous
//
#include <hip/hip_runtime.h>
#include <math.h>

#define NT 512
#define QDIM 4096   // 2^12

using F2 = float2;

__device__ __forceinline__ F2 cadd(F2 p, F2 q) { return make_float2(p.x + q.x, p.y + q.y); }
__device__ __forceinline__ F2 cmul(F2 p, F2 q) {
    return make_float2(p.x * q.x - p.y * q.y, p.x * q.y + p.y * q.x);
}

struct M2 { F2 a, b, c, d; };  // [[a,b],[c,d]]

__device__ __forceinline__ M2 mmul(M2 A, M2 B) {
    M2 R;
    R.a = cadd(cmul(A.a, B.a), cmul(A.b, B.c));
    R.b = cadd(cmul(A.a, B.b), cmul(A.b, B.d));
    R.c = cadd(cmul(A.c, B.a), cmul(A.d, B.c));
    R.d = cadd(cmul(A.c, B.b), cmul(A.d, B.d));
    return R;
}

__device__ __forceinline__ M2 mrx(float t) {
    float s, c; sincosf(0.5f * t, &s, &c);
    return { make_float2(c, 0), make_float2(0, -s), make_float2(0, -s), make_float2(c, 0) };
}
__device__ __forceinline__ M2 mry(float t) {
    float s, c; sincosf(0.5f * t, &s, &c);
    return { make_float2(c, 0), make_float2(-s, 0), make_float2(s, 0), make_float2(c, 0) };
}
__device__ __forceinline__ M2 mrz(float t) {
    float s, c; sincosf(0.5f * t, &s, &c);
    return { make_float2(c, -s), make_float2(0, 0), make_float2(0, 0), make_float2(c, s) };
}

#define RSQ2 0.70710678118654752f
__device__ __forceinline__ M2 mH() {   // H
    return { make_float2(RSQ2, 0), make_float2(RSQ2, 0), make_float2(RSQ2, 0), make_float2(-RSQ2, 0) };
}
__device__ __forceinline__ M2 mW() {   // W = H*S; W† Z W = -Y => YY = W†⊗W† ZZ W⊗W
    return { make_float2(RSQ2, 0), make_float2(0, RSQ2), make_float2(RSQ2, 0), make_float2(0, -RSQ2) };
}
__device__ __forceinline__ M2 mWd() {  // W†
    return { make_float2(RSQ2, 0), make_float2(RSQ2, 0), make_float2(0, -RSQ2), make_float2(0, RSQ2) };
}

// ================= layout ladder =================
// Layout Li: register-local j = qubits {3Li, 3Li+1, 3Li+2};
// t = the other 9 qubit bits of k packed low-to-high (t = lanes(6) | waves(3)).
// LDS slot: slot_L(k) = j*512 + (t ^ j)   (XOR breaks trip-read bank aliasing)

template<int Li>
__device__ __forceinline__ int kOf(int t, int j) {
    const int mlo = (1 << (3 * Li)) - 1;
    return (t & mlo) | (j << (3 * Li)) | ((t & ~mlo) << 3);
}
template<int Li>
__device__ __forceinline__ int slotOf(int k) {
    const int mlo = (1 << (3 * Li)) - 1;
    int j = (k >> (3 * Li)) & 7;
    int t = (k & mlo) | ((k >> 3) & ~mlo);
    return j * 512 + (t ^ j);
}

// move register triple from layout LA to layout LB (1 barrier, double-buffered)
template<int LA, int LB>
__device__ __forceinline__ void trip(F2* amp, int tid, F2* b) {
#pragma unroll
    for (int j = 0; j < 8; ++j) b[j * 512 + (tid ^ j)] = amp[j];
    __syncthreads();
#pragma unroll
    for (int j = 0; j < 8; ++j) amp[j] = b[slotOf<LA>(kOf<LB>(tid, j))];
}

// 1q register gate on local j-bit JB
template<int JB>
__device__ __forceinline__ void g1_reg(F2* amp, const F2* g) {
    const int m = 1 << JB;
    F2 m00 = g[0], m01 = g[1], m10 = g[2], m11 = g[3];
#pragma unroll
    for (int j = 0; j < 8; ++j)
        if (!(j & m)) {
            F2 a = amp[j], b = amp[j | m];
            amp[j]     = cadd(cmul(m00, a), cmul(m01, b));
            amp[j | m] = cadd(cmul(m10, a), cmul(m11, b));
        }
}

// fused diagonal Ising phase (all 12 ring edges) in L3: k = (j<<9) | tid
// edges: e<11 -> (11-e, 10-e); e=11 -> (11,0)
__device__ __forceinline__ void diag_L3(F2* amp, const float* zh, int tid) {
    float phi0 = 0.f;
#pragma unroll
    for (int e = 3; e <= 10; ++e) {   // edges entirely in tid bits: thread-constant
        int hi = 11 - e, lo = 10 - e;
        phi0 += (((tid >> hi) ^ (tid >> lo)) & 1) ? zh[e] : -zh[e];
    }
    float z0 = zh[0], z1 = zh[1], z2 = zh[2], z11 = zh[11];
    int t8 = (tid >> 8) & 1, t0 = tid & 1;
#pragma unroll
    for (int j = 0; j < 8; ++j) {
        int j0 = j & 1, j1 = (j >> 1) & 1, j2 = (j >> 2) & 1;
        float phi = phi0
            + ((j2 ^ j1) ? z0 : -z0)       // (11,10)
            + ((j1 ^ j0) ? z1 : -z1)       // (10,9)
            + ((j0 ^ t8) ? z2 : -z2)       // (9,8)
            + ((j2 ^ t0) ? z11 : -z11);    // (11,0)
        float sp, cp;
        __sincosf(phi, &sp, &cp);
        amp[j] = cmul(amp[j], make_float2(cp, sp));
    }
}

// composed CNOT-ring source index (sequential ring fused to one permutation)
__device__ __forceinline__ int cnot_src(int k) {
#pragma unroll
    for (int e = 11; e >= 0; --e) {
        int hi = (e < 11) ? 11 - e : 11, lo = (e < 11) ? 10 - e : 0;
        if ((k >> hi) & 1) k ^= (1 << lo);
    }
    return k;
}

__device__ __forceinline__ void cnot_trip(F2* amp, int tid, const int* kslot, F2* b) {
#pragma unroll
    for (int j = 0; j < 8; ++j) b[j * 512 + (tid ^ j)] = amp[j];  // L0 write
    __syncthreads();
#pragma unroll
    for (int j = 0; j < 8; ++j) amp[j] = b[kslot[j]];             // lands in L0
}

__global__ __launch_bounds__(NT) void qsim_kernel(
    const float* __restrict__ data,       // [64,12]
    const float* __restrict__ enc_scale,  // [12,3]
    const float* __restrict__ enc_bias,   // [12,3]
    const float* __restrict__ eta,        // [1,3]
    const float* __restrict__ ew_zz,      // [1,12]
    const float* __restrict__ ew_xx,      // [1,12]
    const float* __restrict__ ew_yy,      // [1,12]
    const float* __restrict__ nb_z,       // [1,12]
    const float* __restrict__ nb_x,       // [1,12]
    const float* __restrict__ nb_y,       // [1,12]
    const float* __restrict__ trots,      // [1,3,12,3]
    float* __restrict__ out)              // [64,12]
{
    __shared__ F2 buf[2][QDIM];    // 64 KB double buffer
    __shared__ F2 g1q[72][4];      // fused 1q matrices: enc [b*12+q], bias+trots [36+b*12+q]
    __shared__ float zhalf[3][12]; // theta/2 per block, per edge
    __shared__ float red[8][12];

    const int tid = threadIdx.x;
    const int bat = blockIdx.x;

    // ---- fused gate tables (Ising basis changes folded into neighbors) ----
    if (tid < 36) {                      // encoding: b = tid/12, q = tid%12
        int b = tid / 12, q = tid % 12;
        float x  = data[bat * 12 + q];
        float ax = enc_scale[q * 3 + 0] * x + enc_bias[q * 3 + 0];
        float ay = enc_scale[q * 3 + 1] * x + enc_bias[q * 3 + 1];
        float az = enc_scale[q * 3 + 2] * x + enc_bias[q * 3 + 2];
        M2 M;
        if (b == 0)      M = mmul(mrz(az), mmul(mry(ay), mrx(ax)));   // ZZ: no basis change
        else if (b == 1) M = mmul(mH(), mmul(mry(ay), mrx(ax)));      // XX: H after enc
        else             M = mmul(mW(), mmul(mrz(az), mry(ay)));      // YY: W after enc
        g1q[tid][0] = M.a; g1q[tid][1] = M.b; g1q[tid][2] = M.c; g1q[tid][3] = M.d;
    } else if (tid < 72) {               // bias + trainables (+ closing basis change first)
        int i = tid - 36, b = i / 12, q = i % 12;
        float nb = (b == 0) ? nb_z[q] : (b == 1) ? nb_x[q] : nb_y[q];
        M2 M0 = (b == 0) ? mrz(nb) : (b == 1) ? mrx(nb) : mry(nb);
        float t0 = trots[(b * 12 + q) * 3 + 0];
        float t1 = trots[(b * 12 + q) * 3 + 1];
        float t2 = trots[(b * 12 + q) * 3 + 2];
        M2 M = mmul(mrz(t2), mmul(mry(t1), mmul(mrx(t0), M0)));
        if (b == 1)      M = mmul(M, mH());    // closes the XX sandwich
        else if (b == 2) M = mmul(M, mWd());   // closes the YY sandwich
        g1q[tid][0] = M.a; g1q[tid][1] = M.b; g1q[tid][2] = M.c; g1q[tid][3] = M.d;
    } else if (tid < 108) {              // diagonal half-angles per block/edge
        int i = tid - 72, b = i / 12, e = i % 12;
        const float* ew = (b == 0) ? ew_zz : (b == 1) ? ew_xx : ew_yy;
        zhalf[b][e] = 0.5f * eta[b] * ew[e];
    }
    __syncthreads();

    // ---- state: L0 (j = q0-2), k = kOf<0>(tid, j) = (tid<<3)|j ----
    F2 amp[8];
#pragma unroll
    for (int j = 0; j < 8; ++j) amp[j] = make_float2(0.f, 0.f);
    if (tid == 0) amp[0].x = 1.f;

    // precompute CNOT-ring gather slots (same permutation every block)
    int kslot[8];
#pragma unroll
    for (int j = 0; j < 8; ++j)
        kslot[j] = slotOf<0>(cnot_src(kOf<0>(tid, j)));

    int sel = 0;
#define NB (&buf[(sel ^= 1) ^ 1][0])

    for (int blk = 0; blk < 3; ++blk) {
        const F2(*Ge)[4] = &g1q[blk * 12];
        const F2(*Gb)[4] = &g1q[36 + blk * 12];

        // ---- encoding (+opening basis change): ladder L0 -> L3 ----
        g1_reg<0>(amp, Ge[0]);  g1_reg<1>(amp, Ge[1]);  g1_reg<2>(amp, Ge[2]);
        trip<0,1>(amp, tid, NB);
        g1_reg<0>(amp, Ge[3]);  g1_reg<1>(amp, Ge[4]);  g1_reg<2>(amp, Ge[5]);
        trip<1,2>(amp, tid, NB);
        g1_reg<0>(amp, Ge[6]);  g1_reg<1>(amp, Ge[7]);  g1_reg<2>(amp, Ge[8]);
        trip<2,3>(amp, tid, NB);
        g1_reg<0>(amp, Ge[9]);  g1_reg<1>(amp, Ge[10]); g1_reg<2>(amp, Ge[11]);

        // ---- Ising block == fused diagonal in the rotated basis (L3) ----
        diag_L3(amp, zhalf[blk], tid);

        // ---- (closing basis change+) bias + trots: ladder L3 -> L0 ----
        g1_reg<0>(amp, Gb[9]);  g1_reg<1>(amp, Gb[10]); g1_reg<2>(amp, Gb[11]);
        trip<3,2>(amp, tid, NB);
        g1_reg<0>(amp, Gb[6]);  g1_reg<1>(amp, Gb[7]);  g1_reg<2>(amp, Gb[8]);
        trip<2,1>(amp, tid, NB);
        g1_reg<0>(amp, Gb[3]);  g1_reg<1>(amp, Gb[4]);  g1_reg<2>(amp, Gb[5]);
        trip<1,0>(amp, tid, NB);
        g1_reg<0>(amp, Gb[0]);  g1_reg<1>(amp, Gb[1]);  g1_reg<2>(amp, Gb[2]);

        // ---- CNOT entangling ring (fused permutation, stays L0) ----
        cnot_trip(amp, tid, kslot, NB);
    }

    // ---- Pauli-Z expectations (state in L0: k = (tid<<3)|j) ----
    // outputs i=0..8 <- sign from tid bit (8-i); i=9,10,11 <- sign from j bits 2,1,0
    float pr[8];
#pragma unroll
    for (int j = 0; j < 8; ++j) pr[j] = amp[j].x * amp[j].x + amp[j].y * amp[j].y;
    float psum = 0.f;
#pragma unroll
    for (int j = 0; j < 8; ++j) psum += pr[j];

    float acc[12];
#pragma unroll
    for (int i = 0; i < 9; ++i)
        acc[i] = ((tid >> (8 - i)) & 1) ? -psum : psum;
#pragma unroll
    for (int i = 9; i < 12; ++i) {
        float s = 0.f;
        int bit = 11 - i;  // j-bit index
#pragma unroll
        for (int j = 0; j < 8; ++j)
            s += ((j >> bit) & 1) ? -pr[j] : pr[j];
        acc[i] = s;
    }
#pragma unroll
    for (int off = 32; off > 0; off >>= 1)
#pragma unroll
        for (int i = 0; i < 12; ++i)
            acc[i] += __shfl_down(acc[i], off, 64);
    int wv = tid >> 6;
    if ((tid & 63) == 0)
#pragma unroll
        for (int i = 0; i < 12; ++i) red[wv][i] = acc[i];
    __syncthreads();
    if (tid < 12) {
        float s = 0.f;
#pragma unroll
        for (int ww = 0; ww < 8; ++ww) s += red[ww][tid];
        out[bat * 12 + tid] = s;
    }
}

extern "C" void kernel_launch(void* const* d_in, const int* in_sizes, int n_in,
                              void* d_out, int out_size, void* d_ws, size_t ws_size,
                              hipStream_t stream) {
    const float* data      = (const float*)d_in[0];
    const float* enc_scale = (const float*)d_in[1];
    const float* enc_bias  = (const float*)d_in[2];
    const float* eta       = (const float*)d_in[3];
    const float* ew_zz     = (const float*)d_in[4];
    const float* ew_xx     = (const float*)d_in[5];
    const float* ew_yy     = (const float*)d_in[6];
    const float* nb_z      = (const float*)d_in[7];
    const float* nb_x      = (const float*)d_in[8];
    const float* nb_y      = (const float*)d_in[9];
    const float* trots     = (const float*)d_in[10];
    float* out = (float*)d_out;

    int batch = out_size / 12;  // 64
    qsim_kernel<<<batch, NT, 0, stream>>>(data, enc_scale, enc_bias, eta,
                                          ew_zz, ew_xx, ew_yy,
                                          nb_z, nb_x, nb_y, trots, out);
}

// Round 6
// 100.297 us; speedup vs baseline: 2.0195x; 1.0296x over previous
//
#include <hip/hip_runtime.h>
#include <math.h>

#define NT 512
#define QDIM 4096   // 2^12

using F2 = float2;

__device__ __forceinline__ F2 cadd(F2 p, F2 q) { return make_float2(p.x + q.x, p.y + q.y); }
__device__ __forceinline__ F2 cmul(F2 p, F2 q) {
    return make_float2(p.x * q.x - p.y * q.y, p.x * q.y + p.y * q.x);
}

struct M2 { F2 a, b, c, d; };  // [[a,b],[c,d]]

__device__ __forceinline__ M2 mmul(M2 A, M2 B) {
    M2 R;
    R.a = cadd(cmul(A.a, B.a), cmul(A.b, B.c));
    R.b = cadd(cmul(A.a, B.b), cmul(A.b, B.d));
    R.c = cadd(cmul(A.c, B.a), cmul(A.d, B.c));
    R.d = cadd(cmul(A.c, B.b), cmul(A.d, B.d));
    return R;
}

__device__ __forceinline__ M2 mrx(float t) {
    float s, c; sincosf(0.5f * t, &s, &c);
    return { make_float2(c, 0), make_float2(0, -s), make_float2(0, -s), make_float2(c, 0) };
}
__device__ __forceinline__ M2 mry(float t) {
    float s, c; sincosf(0.5f * t, &s, &c);
    return { make_float2(c, 0), make_float2(-s, 0), make_float2(s, 0), make_float2(c, 0) };
}
__device__ __forceinline__ M2 mrz(float t) {
    float s, c; sincosf(0.5f * t, &s, &c);
    return { make_float2(c, -s), make_float2(0, 0), make_float2(0, 0), make_float2(c, s) };
}

#define RSQ2 0.70710678118654752f
__device__ __forceinline__ M2 mH() {   // H
    return { make_float2(RSQ2, 0), make_float2(RSQ2, 0), make_float2(RSQ2, 0), make_float2(-RSQ2, 0) };
}
__device__ __forceinline__ M2 mW() {   // W = H*S; W† Z W = -Y => YY = W†⊗W† ZZ W⊗W
    return { make_float2(RSQ2, 0), make_float2(0, RSQ2), make_float2(RSQ2, 0), make_float2(0, -RSQ2) };
}
__device__ __forceinline__ M2 mWd() {  // W†
    return { make_float2(RSQ2, 0), make_float2(RSQ2, 0), make_float2(0, -RSQ2), make_float2(0, RSQ2) };
}

// ================= layouts =================
// tid = wv*64 + l.  Layout Li: register-local j = qubits {3Li..3Li+2}
// L0: k = j | l<<3 | wv<<9          L1: k = (l&7) | j<<3 | (l>>3)<<6 | wv<<9
// L2: k = l | j<<6 | wv<<9          L3: k = l | wv<<6 | j<<9
// Trips <0,1>,<1,2> (and inverses) exchange j with LANE bits -> intra-wave, no barrier.
// Trip <2,3>/<3,2> exchanges j with WAVE bits -> workgroup barrier.

template<int Li>
__device__ __forceinline__ int kOf(int t, int j) {
    const int mlo = (1 << (3 * Li)) - 1;
    return (t & mlo) | (j << (3 * Li)) | ((t & ~mlo) << 3);
}
__device__ __forceinline__ int slot0(int k) {   // L0 barrier-buffer slot (matches btrip writes)
    int j = k & 7, t = k >> 3;
    return j * 512 + (t ^ j);
}

// ---- intra-wave trips (wave-private 512-F2 region wb, NO barrier) ----
// wave-region slot(j,l) = j*64 + (l ^ (9j & 63))  — bank-residues equidistributed
template<int TYPE>   // TYPE 0: <0,1>/<1,0>   TYPE 1: <1,2>/<2,1>
__device__ __forceinline__ void itrip(F2* amp, int l, F2* wb) {
#pragma unroll
    for (int j = 0; j < 8; ++j) wb[j * 64 + (l ^ ((9 * j) & 63))] = amp[j];
    asm volatile("" ::: "memory");   // compiler fence; DS pipe is in-order per wave
#pragma unroll
    for (int j = 0; j < 8; ++j) {
        int jo, lo;
        if (TYPE == 0) { jo = l & 7;        lo = j | (l & 56); }
        else           { jo = (l >> 3) & 7; lo = (l & 7) | (j << 3); }
        amp[j] = wb[jo * 64 + (lo ^ ((9 * jo) & 63))];
    }
}

// ---- barrier trip <2,3> / <3,2> (involution: same formula both ways) ----
__device__ __forceinline__ void btrip(F2* amp, int tid, int l, int wv, F2* b) {
#pragma unroll
    for (int j = 0; j < 8; ++j) b[j * 512 + (tid ^ j)] = amp[j];
    __syncthreads();
#pragma unroll
    for (int j = 0; j < 8; ++j) amp[j] = b[wv * 512 + ((j * 64 + l) ^ wv)];
}

// ---- 1q register gate on local j-bit JB ----
template<int JB>
__device__ __forceinline__ void g1_reg(F2* amp, const F2* g) {
    const int m = 1 << JB;
    F2 m00 = g[0], m01 = g[1], m10 = g[2], m11 = g[3];
#pragma unroll
    for (int j = 0; j < 8; ++j)
        if (!(j & m)) {
            F2 a = amp[j], b = amp[j | m];
            amp[j]     = cadd(cmul(m00, a), cmul(m01, b));
            amp[j | m] = cadd(cmul(m10, a), cmul(m11, b));
        }
}

// ---- fused diagonal Ising phase (all 12 ring edges) in L3: k = tid(0-8) | j<<9 ----
__device__ __forceinline__ void diag_L3(F2* amp, const float* zh, int tid) {
    float phi0 = 0.f;
#pragma unroll
    for (int e = 3; e <= 10; ++e) {   // edges entirely in tid bits: thread-constant
        int hi = 11 - e, lo = 10 - e;
        phi0 += (((tid >> hi) ^ (tid >> lo)) & 1) ? zh[e] : -zh[e];
    }
    float z0 = zh[0], z1 = zh[1], z2 = zh[2], z11 = zh[11];
    int t8 = (tid >> 8) & 1, t0 = tid & 1;
#pragma unroll
    for (int j = 0; j < 8; ++j) {
        int j0 = j & 1, j1 = (j >> 1) & 1, j2 = (j >> 2) & 1;
        float phi = phi0
            + ((j2 ^ j1) ? z0 : -z0)       // (11,10)
            + ((j1 ^ j0) ? z1 : -z1)       // (10,9)
            + ((j0 ^ t8) ? z2 : -z2)       // (9,8)
            + ((j2 ^ t0) ? z11 : -z11);    // (11,0)
        float sp, cp;
        __sincosf(phi, &sp, &cp);
        amp[j] = cmul(amp[j], make_float2(cp, sp));
    }
}

// ---- composed CNOT-ring source index ----
__device__ __forceinline__ int cnot_src(int k) {
#pragma unroll
    for (int e = 11; e >= 0; --e) {
        int hi = (e < 11) ? 11 - e : 11, lo = (e < 11) ? 10 - e : 0;
        if ((k >> hi) & 1) k ^= (1 << lo);
    }
    return k;
}

__device__ __forceinline__ void cnot_trip(F2* amp, int tid, const int* kslot, F2* b) {
#pragma unroll
    for (int j = 0; j < 8; ++j) b[j * 512 + (tid ^ j)] = amp[j];  // L0 write
    __syncthreads();
#pragma unroll
    for (int j = 0; j < 8; ++j) amp[j] = b[kslot[j]];             // lands in L0
}

__global__ __launch_bounds__(NT) void qsim_kernel(
    const float* __restrict__ data,       // [64,12]
    const float* __restrict__ enc_scale,  // [12,3]
    const float* __restrict__ enc_bias,   // [12,3]
    const float* __restrict__ eta,        // [1,3]
    const float* __restrict__ ew_zz,      // [1,12]
    const float* __restrict__ ew_xx,      // [1,12]
    const float* __restrict__ ew_yy,      // [1,12]
    const float* __restrict__ nb_z,       // [1,12]
    const float* __restrict__ nb_x,       // [1,12]
    const float* __restrict__ nb_y,       // [1,12]
    const float* __restrict__ trots,      // [1,3,12,3]
    float* __restrict__ out)              // [64,12]
{
    __shared__ F2 bbuf[2][QDIM];   // 64 KB barrier double buffer
    __shared__ F2 ibuf[QDIM];      // 32 KB intra-wave buffer (512 F2 per wave)
    __shared__ F2 g1q[72][4];      // fused 1q matrices
    __shared__ float zhalf[3][12];
    __shared__ float red[8][12];

    const int tid = threadIdx.x;
    const int l = tid & 63, wv = tid >> 6;
    const int bat = blockIdx.x;
    F2* wb = &ibuf[wv * 512];      // wave-private region

    // ---- fused gate tables (Ising basis changes folded into neighbors) ----
    if (tid < 36) {                      // encoding: b = tid/12, q = tid%12
        int b = tid / 12, q = tid % 12;
        float x  = data[bat * 12 + q];
        float ax = enc_scale[q * 3 + 0] * x + enc_bias[q * 3 + 0];
        float ay = enc_scale[q * 3 + 1] * x + enc_bias[q * 3 + 1];
        float az = enc_scale[q * 3 + 2] * x + enc_bias[q * 3 + 2];
        M2 M;
        if (b == 0)      M = mmul(mrz(az), mmul(mry(ay), mrx(ax)));   // ZZ: no basis change
        else if (b == 1) M = mmul(mH(), mmul(mry(ay), mrx(ax)));      // XX: H after enc
        else             M = mmul(mW(), mmul(mrz(az), mry(ay)));      // YY: W after enc
        g1q[tid][0] = M.a; g1q[tid][1] = M.b; g1q[tid][2] = M.c; g1q[tid][3] = M.d;
    } else if (tid < 72) {               // bias + trainables (+ closing basis change first)
        int i = tid - 36, b = i / 12, q = i % 12;
        float nb = (b == 0) ? nb_z[q] : (b == 1) ? nb_x[q] : nb_y[q];
        M2 M0 = (b == 0) ? mrz(nb) : (b == 1) ? mrx(nb) : mry(nb);
        float t0 = trots[(b * 12 + q) * 3 + 0];
        float t1 = trots[(b * 12 + q) * 3 + 1];
        float t2 = trots[(b * 12 + q) * 3 + 2];
        M2 M = mmul(mrz(t2), mmul(mry(t1), mmul(mrx(t0), M0)));
        if (b == 1)      M = mmul(M, mH());    // closes the XX sandwich
        else if (b == 2) M = mmul(M, mWd());   // closes the YY sandwich
        g1q[tid][0] = M.a; g1q[tid][1] = M.b; g1q[tid][2] = M.c; g1q[tid][3] = M.d;
    } else if (tid < 108) {              // diagonal half-angles per block/edge
        int i = tid - 72, b = i / 12, e = i % 12;
        const float* ew = (b == 0) ? ew_zz : (b == 1) ? ew_xx : ew_yy;
        zhalf[b][e] = 0.5f * eta[b] * ew[e];
    }
    __syncthreads();

    // ---- state: L0, k = (tid<<3)|j ----
    F2 amp[8];
#pragma unroll
    for (int j = 0; j < 8; ++j) amp[j] = make_float2(0.f, 0.f);
    if (tid == 0) amp[0].x = 1.f;

    // precompute CNOT-ring gather slots (same permutation every block)
    int kslot[8];
#pragma unroll
    for (int j = 0; j < 8; ++j)
        kslot[j] = slot0(cnot_src(kOf<0>(tid, j)));

    int sel = 0;
#define NB (&bbuf[(sel ^= 1) ^ 1][0])

    for (int blk = 0; blk < 3; ++blk) {
        const F2(*Ge)[4] = &g1q[blk * 12];
        const F2(*Gb)[4] = &g1q[36 + blk * 12];

        // ---- encoding (+opening basis change): L0 -> L1 -> L2 -> L3 ----
        g1_reg<0>(amp, Ge[0]);  g1_reg<1>(amp, Ge[1]);  g1_reg<2>(amp, Ge[2]);
        itrip<0>(amp, l, wb);                       // L0 -> L1 (no barrier)
        g1_reg<0>(amp, Ge[3]);  g1_reg<1>(amp, Ge[4]);  g1_reg<2>(amp, Ge[5]);
        itrip<1>(amp, l, wb);                       // L1 -> L2 (no barrier)
        g1_reg<0>(amp, Ge[6]);  g1_reg<1>(amp, Ge[7]);  g1_reg<2>(amp, Ge[8]);
        btrip(amp, tid, l, wv, NB);                 // L2 -> L3 (barrier)
        g1_reg<0>(amp, Ge[9]);  g1_reg<1>(amp, Ge[10]); g1_reg<2>(amp, Ge[11]);

        // ---- Ising block == fused diagonal in the rotated basis (L3) ----
        diag_L3(amp, zhalf[blk], tid);

        // ---- (closing basis change+) bias + trots: L3 -> L2 -> L1 -> L0 ----
        g1_reg<0>(amp, Gb[9]);  g1_reg<1>(amp, Gb[10]); g1_reg<2>(amp, Gb[11]);
        btrip(amp, tid, l, wv, NB);                 // L3 -> L2 (barrier)
        g1_reg<0>(amp, Gb[6]);  g1_reg<1>(amp, Gb[7]);  g1_reg<2>(amp, Gb[8]);
        itrip<1>(amp, l, wb);                       // L2 -> L1 (no barrier)
        g1_reg<0>(amp, Gb[3]);  g1_reg<1>(amp, Gb[4]);  g1_reg<2>(amp, Gb[5]);
        itrip<0>(amp, l, wb);                       // L1 -> L0 (no barrier)
        g1_reg<0>(amp, Gb[0]);  g1_reg<1>(amp, Gb[1]);  g1_reg<2>(amp, Gb[2]);

        // ---- CNOT entangling ring (fused permutation, stays L0; barrier) ----
        cnot_trip(amp, tid, kslot, NB);
    }

    // ---- Pauli-Z expectations (state in L0: k = (tid<<3)|j) ----
    float pr[8];
#pragma unroll
    for (int j = 0; j < 8; ++j) pr[j] = amp[j].x * amp[j].x + amp[j].y * amp[j].y;
    float psum = 0.f;
#pragma unroll
    for (int j = 0; j < 8; ++j) psum += pr[j];

    float acc[12];
#pragma unroll
    for (int i = 0; i < 9; ++i)
        acc[i] = ((tid >> (8 - i)) & 1) ? -psum : psum;
#pragma unroll
    for (int i = 9; i < 12; ++i) {
        float s = 0.f;
        int bit = 11 - i;  // j-bit index
#pragma unroll
        for (int j = 0; j < 8; ++j)
            s += ((j >> bit) & 1) ? -pr[j] : pr[j];
        acc[i] = s;
    }
#pragma unroll
    for (int off = 32; off > 0; off >>= 1)
#pragma unroll
        for (int i = 0; i < 12; ++i)
            acc[i] += __shfl_down(acc[i], off, 64);
    if ((tid & 63) == 0)
#pragma unroll
        for (int i = 0; i < 12; ++i) red[wv][i] = acc[i];
    __syncthreads();
    if (tid < 12) {
        float s = 0.f;
#pragma unroll
        for (int ww = 0; ww < 8; ++ww) s += red[ww][tid];
        out[bat * 12 + tid] = s;
    }
}

extern "C" void kernel_launch(void* const* d_in, const int* in_sizes, int n_in,
                              void* d_out, int out_size, void* d_ws, size_t ws_size,
                              hipStream_t stream) {
    const float* data      = (const float*)d_in[0];
    const float* enc_scale = (const float*)d_in[1];
    const float* enc_bias  = (const float*)d_in[2];
    const float* eta       = (const float*)d_in[3];
    const float* ew_zz     = (const float*)d_in[4];
    const float* ew_xx     = (const float*)d_in[5];
    const float* ew_yy     = (const float*)d_in[6];
    const float* nb_z      = (const float*)d_in[7];
    const float* nb_x      = (const float*)d_in[8];
    const float* nb_y      = (const float*)d_in[9];
    const float* trots     = (const float*)d_in[10];
    float* out = (float*)d_out;

    int batch = out_size / 12;  // 64
    qsim_kernel<<<batch, NT, 0, stream>>>(data, enc_scale, enc_bias, eta,
                                          ew_zz, ew_xx, ew_yy,
                                          nb_z, nb_x, nb_y, trots, out);
}